// Round 1
// 387.914 us; speedup vs baseline: 1.1810x; 1.1810x over previous
//
#include <hip/hip_runtime.h>
#include <hip/hip_bf16.h>

typedef __hip_bfloat16 bf16;
typedef __attribute__((ext_vector_type(8))) short short8;
typedef __attribute__((ext_vector_type(4))) float floatx4;

#define NVP 10242
#define NV  40962
#define NF  81920
#define VPB 16
#define FPW 4   // faces per wave in k_facegrad

__device__ __forceinline__ float bfbits2f(unsigned short u) {
    union { unsigned int i; float f; } cv; cv.i = ((unsigned int)u) << 16;
    return cv.f;
}
__device__ __forceinline__ unsigned short f2bfbits(float f) {
    bf16 h = __float2bfloat16(f);
    return __builtin_bit_cast(unsigned short, h);
}
// fp8 e4m3 (OCP on gfx950)
__device__ __forceinline__ unsigned short pk_fp8(float a, float b) {
    int p = __builtin_amdgcn_cvt_pk_fp8_f32(a, b, 0, false);
    return (unsigned short)(p & 0xffff);
}
__device__ __forceinline__ unsigned char one_fp8(float a) {
    int p = __builtin_amdgcn_cvt_pk_fp8_f32(a, 0.f, 0, false);
    return (unsigned char)(p & 0xff);
}
__device__ __forceinline__ float fp8_lo(unsigned int u) {
    return __builtin_amdgcn_cvt_f32_fp8(u, 0);
}
__device__ __forceinline__ float fp8_hi(unsigned int u) {
    return __builtin_amdgcn_cvt_f32_fp8(u, 1);
}

// ---------------------------------------------------------------------------
// K0: coeffs [o][c][k] -> coeffsB bf16 in MFMA 16x16x32 B-fragment layout
// ---------------------------------------------------------------------------
__global__ void k_coeffsB(const float* __restrict__ coeffs,
                          unsigned short* __restrict__ coeffsB) {
    int t = blockIdx.x * 256 + threadIdx.x;       // 0..16383
    int j = t & 7, lane = (t >> 3) & 63, s = t >> 9;   // s = ot*8+kk
    int ot = s >> 3, kk = s & 7;
    int o  = ot * 16 + (lane & 15);
    int kg = kk * 32 + (lane >> 4) * 8 + j;
    coeffsB[t] = f2bfbits(coeffs[o * 256 + kg]);
}

// ---------------------------------------------------------------------------
// K0b: pack per-face scalar operands into ONE 96 B record (batch-invariant):
// [9 cols (int bits) | 9 vals | EW[3] | NS[3]]  -> 2-3 wide s_loads per face
// instead of ~18 scattered s_loads across 5 streams.
// ---------------------------------------------------------------------------
__global__ void k_packG(const int* __restrict__ G_cols,
                        const float* __restrict__ G_vals,
                        const float* __restrict__ EW,
                        const float* __restrict__ NS,
                        float* __restrict__ Gpk) {
    int f = blockIdx.x * 256 + threadIdx.x;       // NF/256 = 320 exact
    float r[24];
#pragma unroll
    for (int d = 0; d < 3; ++d)
#pragma unroll
        for (int j = 0; j < 3; ++j) {
            int idx = (d * NF + f) * 3 + j;
            r[d * 3 + j]     = __int_as_float(G_cols[idx]);
            r[9 + d * 3 + j] = G_vals[idx];
        }
#pragma unroll
    for (int d = 0; d < 3; ++d) {
        r[18 + d] = EW[f * 3 + d];
        r[21 + d] = NS[f * 3 + d];
    }
    float4* dst = (float4*)(Gpk + (size_t)f * 24);   // f*96 B, 16B-aligned
#pragma unroll
    for (int q = 0; q < 6; ++q) dst[q] = ((const float4*)r)[q];
}

// ---------------------------------------------------------------------------
// K0c: pack per-vertex scalar operands into ONE 112 B record (pad to 16B):
// [7 Lcols | 7 Lvals | 6 F2Vcols | 6 F2Vvals | pad2]
// ---------------------------------------------------------------------------
__global__ void k_packV(const int* __restrict__ L_cols,
                        const float* __restrict__ L_vals,
                        const int* __restrict__ F2V_cols,
                        const float* __restrict__ F2V_vals,
                        float* __restrict__ Vpk) {
    int v = blockIdx.x * 256 + threadIdx.x;
    if (v >= NV) return;
    float r[28];
#pragma unroll
    for (int j = 0; j < 7; ++j) {
        r[j]     = __int_as_float(L_cols[v * 7 + j]);
        r[7 + j] = L_vals[v * 7 + j];
    }
#pragma unroll
    for (int j = 0; j < 6; ++j) {
        r[14 + j] = __int_as_float(F2V_cols[v * 6 + j]);
        r[20 + j] = F2V_vals[v * 6 + j];
    }
    r[26] = 0.f; r[27] = 0.f;
    float4* dst = (float4*)(Vpk + (size_t)v * 28);   // v*112 B, 16B-aligned
#pragma unroll
    for (int q = 0; q < 7; ++q) dst[q] = ((const float4*)r)[q];
}

// ---------------------------------------------------------------------------
// K1: per-b transpose + pad: x[c][v] fp32 -> xin[v][c] bf16 + xin8[v][c] fp8.
// ---------------------------------------------------------------------------
__global__ void k_transpose(const float* __restrict__ x,
                            unsigned short* __restrict__ xin,
                            unsigned char* __restrict__ xin8) {
    x    += (size_t)blockIdx.y * 64 * NVP;
    xin  += (size_t)blockIdx.y * 64 * NV;
    xin8 += (size_t)blockIdx.y * 64 * NV;
    __shared__ float tile[64][65];
    int v0 = blockIdx.x * 64;
    int tx = threadIdx.x & 63;
    int ty = threadIdx.x >> 6;
    int v  = v0 + tx;
#pragma unroll
    for (int r = 0; r < 16; ++r) {
        int c = ty + r * 4;
        tile[tx][c] = (v < NVP) ? x[c * NVP + v] : 1.0f;
    }
    __syncthreads();
#pragma unroll
    for (int r = 0; r < 16; ++r) {
        int vl = ty + r * 4;
        int vv = v0 + vl;
        if (vv < NV) {
            float val = tile[vl][tx];
            xin [vv * 64 + tx] = f2bfbits(val);
            xin8[vv * 64 + tx] = one_fp8(val);
        }
    }
}

// ---------------------------------------------------------------------------
// K2: face gradients. FPW faces per wave: 4x fewer waves, 36 gathers in
// flight/wave, packed 96 B scalar record -> 1 scalar base, wide s_loads.
// ---------------------------------------------------------------------------
__global__ void __launch_bounds__(256, 8) k_facegrad(
    const unsigned char* __restrict__ xin8,
    const float* __restrict__ Gpk,
    unsigned short* __restrict__ gfi) {
    xin8 += (size_t)blockIdx.y * 64 * NV;
    gfi  += (size_t)blockIdx.y * 64 * NF;
    int w  = __builtin_amdgcn_readfirstlane(threadIdx.x >> 6);
    int c  = threadIdx.x & 63;
    int f0 = (blockIdx.x * 4 + w) * FPW;
#pragma unroll
    for (int i = 0; i < FPW; ++i) {
        int f = f0 + i;
        const float* rf = Gpk + (size_t)f * 24;          // uniform -> s_load
        const unsigned int* ru = (const unsigned int*)rf;
        float xv[9];
#pragma unroll
        for (int j = 0; j < 9; ++j) {
            int col = (int)ru[j];                         // s_load (packed)
            xv[j] = fp8_lo((unsigned int)xin8[col * 64 + c]);
        }
        float g0 = 0.f, g1 = 0.f, g2 = 0.f;
#pragma unroll
        for (int j = 0; j < 3; ++j) {
            g0 += rf[9  + j] * xv[j];
            g1 += rf[12 + j] * xv[3 + j];
            g2 += rf[15 + j] * xv[6 + j];
        }
        float ew = g0 * rf[18] + g1 * rf[19] + g2 * rf[20];
        float ns = g0 * rf[21] + g1 * rf[22] + g2 * rf[23];
        gfi[f * 64 + c] = pk_fp8(ew, ns);                // 128 B/wave store
    }
}

// ---------------------------------------------------------------------------
// K3: vertex kernel. Phase 1 now reads the packed 112 B vertex record
// (3 wide s_loads) instead of 26 scattered s_loads. Rest unchanged.
// ---------------------------------------------------------------------------
__global__ void __launch_bounds__(256) k_vertex(
    const unsigned short* __restrict__ xin,
    const float* __restrict__ Vpk,
    const unsigned short* __restrict__ gfi,
    const unsigned short* __restrict__ coeffsB,
    const float* __restrict__ bias,
    float* __restrict__ out) {
    xin += (size_t)blockIdx.y * 64 * NV;
    gfi += (size_t)blockIdx.y * 64 * NF;
    out += (size_t)blockIdx.y * 64 * NV;
    int vb = blockIdx.x * VPB;

    __shared__ unsigned short feat[VPB * 264];   // 8448 B
    __shared__ float outs[VPB * 65];             // 4160 B
    int w    = threadIdx.x >> 6;
    int lane = threadIdx.x & 63;
    int c    = lane;

    // ---- phase 1: feat build, 4 vertices per wave, packed scalar record ----
#pragma unroll
    for (int i = 0; i < 4; ++i) {
        int vloc = w * 4 + i;
        int v    = vb + vloc;
        int vcs  = __builtin_amdgcn_readfirstlane(v < NV ? v : NV - 1);
        const float* rf = Vpk + (size_t)vcs * 28;        // uniform -> s_load
        const unsigned int* ru = (const unsigned int*)rf;
        float f0 = bfbits2f(xin[vcs * 64 + c]);
        float lap = 0.f;
#pragma unroll
        for (int j = 0; j < 7; ++j) {
            int col = (int)ru[j];
            lap += rf[7 + j] * bfbits2f(xin[col * 64 + c]);
        }
        float ew = 0.f, ns = 0.f;
#pragma unroll
        for (int j = 0; j < 6; ++j) {
            int   col = (int)ru[14 + j];
            float val = rf[20 + j];
            unsigned int u = gfi[col * 64 + c];          // 1 line, both vals
            ew += val * fp8_lo(u);
            ns += val * fp8_hi(u);
        }
        ushort4 p = make_ushort4(f2bfbits(f0), f2bfbits(lap),
                                 f2bfbits(ew), f2bfbits(ns));
        *(ushort4*)&feat[vloc * 264 + c * 4] = p;        // 8B, 2-way (free)
    }
    __syncthreads();

    // ---- phase 2: MFMA, wave w -> o-tile w (o = w*16 .. w*16+15) ----
    int m = lane & 15, quad = lane >> 4;
    float bo = bias[w * 16 + m];
    floatx4 acc = {bo, bo, bo, bo};
#pragma unroll
    for (int kk = 0; kk < 8; ++kk) {
        short8 a = *(const short8*)&feat[m * 264 + kk * 32 + quad * 8];
        short8 bfr = *(const short8*)&coeffsB[((w * 8 + kk) * 64 + lane) * 8];
        acc = __builtin_amdgcn_mfma_f32_16x16x32_bf16(a, bfr, acc, 0, 0, 0);
    }

    // ---- epilogue: C layout col=lane&15 (o), row=quad*4+reg (v) ----
#pragma unroll
    for (int r = 0; r < 4; ++r)
        outs[(quad * 4 + r) * 65 + w * 16 + m] = acc[r];
    __syncthreads();
    int vp = threadIdx.x & 15;
    int og = threadIdx.x >> 4;
    if (vb + vp < NV) {
#pragma unroll
        for (int r = 0; r < 4; ++r) {
            int o2 = og + r * 16;
            out[(size_t)o2 * NV + vb + vp] = outs[vp * 65 + o2];
        }
    }
}

// ---------------------------------------------------------------------------
extern "C" void kernel_launch(void* const* d_in, const int* in_sizes, int n_in,
                              void* d_out, int out_size, void* d_ws, size_t ws_size,
                              hipStream_t stream) {
    const float* x        = (const float*)d_in[0];
    const int*   G_cols   = (const int*)  d_in[2];
    const float* G_vals   = (const float*)d_in[3];
    const int*   L_cols   = (const int*)  d_in[5];
    const float* L_vals   = (const float*)d_in[6];
    const int*   F2V_cols = (const int*)  d_in[8];
    const float* F2V_vals = (const float*)d_in[9];
    const float* EW       = (const float*)d_in[10];
    const float* NS       = (const float*)d_in[11];
    const float* coeffs   = (const float*)d_in[12];
    const float* bias     = (const float*)d_in[13];
    float* out = (float*)d_out;

    char* ws = (char*)d_ws;
    const size_t xin_b = (size_t)NV * 64;   // elements per batch
    const size_t gf_b  = (size_t)NF * 64;
    const size_t gpk_bytes = (size_t)NF * 96;    // 7.86 MB
    const size_t vpk_bytes = (size_t)NV * 112;   // 4.59 MB
    const size_t fixed = 65536 + gpk_bytes + vpk_bytes;
    // per-batch bytes: xin bf16 2*xin_b + gfi 2*gf_b + xin8 1*xin_b
    size_t perb = 2 * xin_b + 2 * gf_b + xin_b;
    int nb = (ws_size >= fixed + 8 * perb) ? 8
           : (ws_size >= fixed + 2 * perb) ? 2 : 1;

    unsigned short* coeffsB = (unsigned short*)ws;            // 32 KB
    float* Gpk = (float*)(ws + 65536);
    float* Vpk = Gpk + (size_t)NF * 24;
    unsigned short* xin  = (unsigned short*)(ws + fixed);     // nb*5.25 MB
    unsigned short* gfi  = xin + (size_t)nb * xin_b;          // nb*10.5 MB
    unsigned char*  xin8 = (unsigned char*)(gfi + (size_t)nb * gf_b); // nb*2.6MB

    k_coeffsB<<<64, 256, 0, stream>>>(coeffs, coeffsB);
    k_packG<<<NF / 256, 256, 0, stream>>>(G_cols, G_vals, EW, NS, Gpk);
    k_packV<<<(NV + 255) / 256, 256, 0, stream>>>(L_cols, L_vals,
                                                  F2V_cols, F2V_vals, Vpk);
    for (int b0 = 0; b0 < 8; b0 += nb) {
        dim3 gt(641, nb), gg(NF / (4 * FPW), nb), gv((NV + VPB - 1) / VPB, nb);
        k_transpose<<<gt, 256, 0, stream>>>(x + (size_t)b0 * 64 * NVP, xin, xin8);
        k_facegrad<<<gg, 256, 0, stream>>>(xin8, Gpk, gfi);
        k_vertex<<<gv, 256, 0, stream>>>(xin, Vpk, gfi, coeffsB, bias,
                                         out + (size_t)b0 * 64 * NV);
    }
}

// Round 2
// 346.976 us; speedup vs baseline: 1.3204x; 1.1180x over previous
//
#include <hip/hip_runtime.h>
#include <hip/hip_bf16.h>

typedef __hip_bfloat16 bf16;
typedef __attribute__((ext_vector_type(8))) short short8;
typedef __attribute__((ext_vector_type(4))) float floatx4;

#define NVP 10242
#define NV  40962
#define NF  81920
#define VPB 32
#define FPW 4   // faces per wave in k_facegrad

__device__ __forceinline__ float bfbits2f(unsigned short u) {
    union { unsigned int i; float f; } cv; cv.i = ((unsigned int)u) << 16;
    return cv.f;
}
__device__ __forceinline__ unsigned short f2bfbits(float f) {
    bf16 h = __float2bfloat16(f);
    return __builtin_bit_cast(unsigned short, h);
}
// fp8 e4m3 (OCP on gfx950)
__device__ __forceinline__ unsigned short pk_fp8(float a, float b) {
    int p = __builtin_amdgcn_cvt_pk_fp8_f32(a, b, 0, false);
    return (unsigned short)(p & 0xffff);
}
__device__ __forceinline__ unsigned char one_fp8(float a) {
    int p = __builtin_amdgcn_cvt_pk_fp8_f32(a, 0.f, 0, false);
    return (unsigned char)(p & 0xff);
}
__device__ __forceinline__ float fp8_lo(unsigned int u) {
    return __builtin_amdgcn_cvt_f32_fp8(u, 0);
}
__device__ __forceinline__ float fp8_hi(unsigned int u) {
    return __builtin_amdgcn_cvt_f32_fp8(u, 1);
}

// ---------------------------------------------------------------------------
// K0: coeffs [o][c][k] -> coeffsB bf16 in MFMA 16x16x32 B-fragment layout
// ---------------------------------------------------------------------------
__global__ void k_coeffsB(const float* __restrict__ coeffs,
                          unsigned short* __restrict__ coeffsB) {
    int t = blockIdx.x * 256 + threadIdx.x;       // 0..16383
    int j = t & 7, lane = (t >> 3) & 63, s = t >> 9;   // s = ot*8+kk
    int ot = s >> 3, kk = s & 7;
    int o  = ot * 16 + (lane & 15);
    int kg = kk * 32 + (lane >> 4) * 8 + j;
    coeffsB[t] = f2bfbits(coeffs[o * 256 + kg]);
}

// ---------------------------------------------------------------------------
// K0b: per-face 128 B record. Layout (dwords):
//   [0..8]   9 cols (int bits)        [9..15]  pad
//   [16..24] 9 vals                   [25..27] EW  [28..30] NS  [31] pad
// Cols-first so ONE s_load_dwordx16 unlocks all 9 gathers of a face.
// ---------------------------------------------------------------------------
__global__ void k_packG(const int* __restrict__ G_cols,
                        const float* __restrict__ G_vals,
                        const float* __restrict__ EW,
                        const float* __restrict__ NS,
                        float* __restrict__ Gpk) {
    int f = blockIdx.x * 256 + threadIdx.x;       // NF/256 = 320 exact
    float r[32];
#pragma unroll
    for (int q = 0; q < 32; ++q) r[q] = 0.f;
#pragma unroll
    for (int d = 0; d < 3; ++d)
#pragma unroll
        for (int j = 0; j < 3; ++j) {
            int idx = (d * NF + f) * 3 + j;
            r[d * 3 + j]      = __int_as_float(G_cols[idx]);
            r[16 + d * 3 + j] = G_vals[idx];
        }
#pragma unroll
    for (int d = 0; d < 3; ++d) {
        r[25 + d] = EW[f * 3 + d];
        r[28 + d] = NS[f * 3 + d];
    }
    float4* dst = (float4*)(Gpk + (size_t)f * 32);   // 128 B, aligned
#pragma unroll
    for (int q = 0; q < 8; ++q) dst[q] = ((const float4*)r)[q];
}

// ---------------------------------------------------------------------------
// K0c: per-vertex 128 B record. Layout (dwords):
//   [0..6]   7 Lcols     [7] pad   [8..13] 6 F2Vcols   [14..15] pad
//   [16..22] 7 Lvals     [23] pad  [24..29] 6 F2Vvals  [30..31] pad
// All cols in first 16 dw -> one s_load_dwordx16 unlocks all 14 gathers.
// ---------------------------------------------------------------------------
__global__ void k_packV(const int* __restrict__ L_cols,
                        const float* __restrict__ L_vals,
                        const int* __restrict__ F2V_cols,
                        const float* __restrict__ F2V_vals,
                        float* __restrict__ Vpk) {
    int v = blockIdx.x * 256 + threadIdx.x;
    if (v >= NV) return;
    float r[32];
#pragma unroll
    for (int q = 0; q < 32; ++q) r[q] = 0.f;
#pragma unroll
    for (int j = 0; j < 7; ++j) {
        r[j]      = __int_as_float(L_cols[v * 7 + j]);
        r[16 + j] = L_vals[v * 7 + j];
    }
#pragma unroll
    for (int j = 0; j < 6; ++j) {
        r[8 + j]  = __int_as_float(F2V_cols[v * 6 + j]);
        r[24 + j] = F2V_vals[v * 6 + j];
    }
    float4* dst = (float4*)(Vpk + (size_t)v * 32);   // 128 B, aligned
#pragma unroll
    for (int q = 0; q < 8; ++q) dst[q] = ((const float4*)r)[q];
}

// ---------------------------------------------------------------------------
// K1: per-b transpose + pad: x[c][v] fp32 -> xin[v][c] bf16 + xin8[v][c] fp8.
// ---------------------------------------------------------------------------
__global__ void k_transpose(const float* __restrict__ x,
                            unsigned short* __restrict__ xin,
                            unsigned char* __restrict__ xin8) {
    x    += (size_t)blockIdx.y * 64 * NVP;
    xin  += (size_t)blockIdx.y * 64 * NV;
    xin8 += (size_t)blockIdx.y * 64 * NV;
    __shared__ float tile[64][65];
    int v0 = blockIdx.x * 64;
    int tx = threadIdx.x & 63;
    int ty = threadIdx.x >> 6;
    int v  = v0 + tx;
#pragma unroll
    for (int r = 0; r < 16; ++r) {
        int c = ty + r * 4;
        tile[tx][c] = (v < NVP) ? x[c * NVP + v] : 1.0f;
    }
    __syncthreads();
#pragma unroll
    for (int r = 0; r < 16; ++r) {
        int vl = ty + r * 4;
        int vv = v0 + vl;
        if (vv < NV) {
            float val = tile[vl][tx];
            xin [vv * 64 + tx] = f2bfbits(val);
            xin8[vv * 64 + tx] = one_fp8(val);
        }
    }
}

// ---------------------------------------------------------------------------
// K2: face gradients. FPW faces/wave, SoA issue order: all 36 gathers first
// (cols chunks via s_load_dwordx16), then vals chunks + math + store.
// launch_bounds(256,4): 128-VGPR cap so the 36 in-flight gathers FIT
// (the old (256,8)=32-VGPR cap forced the compiler to chain faces).
// ---------------------------------------------------------------------------
__global__ void __launch_bounds__(256, 4) k_facegrad(
    const unsigned char* __restrict__ xin8,
    const float* __restrict__ Gpk,
    unsigned short* __restrict__ gfi) {
    xin8 += (size_t)blockIdx.y * 64 * NV;
    gfi  += (size_t)blockIdx.y * 64 * NF;
    int w  = __builtin_amdgcn_readfirstlane(threadIdx.x >> 6);
    int c  = threadIdx.x & 63;
    int f0 = (blockIdx.x * 4 + w) * FPW;
    float xv[FPW][9];
#pragma unroll
    for (int i = 0; i < FPW; ++i) {
        const unsigned int* ru = (const unsigned int*)(Gpk + (size_t)(f0 + i) * 32);
#pragma unroll
        for (int j = 0; j < 9; ++j) {
            int col = (int)ru[j];                        // s_load chunk A
            xv[i][j] = fp8_lo((unsigned int)xin8[col * 64 + c]);
        }
    }
#pragma unroll
    for (int i = 0; i < FPW; ++i) {
        const float* rf = Gpk + (size_t)(f0 + i) * 32;   // s_load chunk B
        float g0 = rf[16] * xv[i][0] + rf[17] * xv[i][1] + rf[18] * xv[i][2];
        float g1 = rf[19] * xv[i][3] + rf[20] * xv[i][4] + rf[21] * xv[i][5];
        float g2 = rf[22] * xv[i][6] + rf[23] * xv[i][7] + rf[24] * xv[i][8];
        float ew = g0 * rf[25] + g1 * rf[26] + g2 * rf[27];
        float ns = g0 * rf[28] + g1 * rf[29] + g2 * rf[30];
        gfi[(f0 + i) * 64 + c] = pk_fp8(ew, ns);         // 128 B/wave store
    }
}

// ---------------------------------------------------------------------------
// K3: vertex kernel. 512 threads, 32 vertices/block. Phase 1 SoA: 4 vertices
// per wave, cols-first records -> ~56 gathers in flight. Laplacian gathers
// now read fp8 xin8 (halves the biggest request stream; 2.6 MB/batch is
// L2-resident). f0 stays bf16. Phase 2: wave (ot, vh) -> o-tile x v-half.
// Epilogue: full 128 B line stores (32 consecutive v per o).
// ---------------------------------------------------------------------------
__global__ void __launch_bounds__(512) k_vertex(
    const unsigned short* __restrict__ xin,
    const unsigned char* __restrict__ xin8,
    const float* __restrict__ Vpk,
    const unsigned short* __restrict__ gfi,
    const unsigned short* __restrict__ coeffsB,
    const float* __restrict__ bias,
    float* __restrict__ out) {
    xin  += (size_t)blockIdx.y * 64 * NV;
    xin8 += (size_t)blockIdx.y * 64 * NV;
    gfi  += (size_t)blockIdx.y * 64 * NF;
    out  += (size_t)blockIdx.y * 64 * NV;
    int vb = blockIdx.x * VPB;

    __shared__ unsigned short feat[VPB * 264];   // 16896 B
    __shared__ float outs[VPB * 65];             // 8320 B
    int w    = __builtin_amdgcn_readfirstlane(threadIdx.x >> 6);  // 0..7
    int lane = threadIdx.x & 63;
    int c    = lane;

    // ---- phase 1: 8 waves x 4 vertices, SoA gather issue ----
    int   vcs[4];
    float f0v[4], lap[4], ewا[4], ns_[4];
#pragma unroll
    for (int i = 0; i < 4; ++i) {
        int v = vb + w * 4 + i;
        vcs[i] = __builtin_amdgcn_readfirstlane(v < NV ? v : NV - 1);
    }
#pragma unroll
    for (int i = 0; i < 4; ++i) {
        const float* rf = Vpk + (size_t)vcs[i] * 32;
        const unsigned int* ru = (const unsigned int*)rf;
        f0v[i] = bfbits2f(xin[vcs[i] * 64 + c]);
        float l = 0.f;
#pragma unroll
        for (int j = 0; j < 7; ++j) {
            int col = (int)ru[j];
            l += rf[16 + j] * fp8_lo((unsigned int)xin8[col * 64 + c]);
        }
        lap[i] = l;
        float e = 0.f, n = 0.f;
#pragma unroll
        for (int j = 0; j < 6; ++j) {
            int   col = (int)ru[8 + j];
            float val = rf[24 + j];
            unsigned int u = gfi[col * 64 + c];          // 1 line, both vals
            e += val * fp8_lo(u);
            n += val * fp8_hi(u);
        }
        ewا[i] = e; ns_[i] = n;
    }
#pragma unroll
    for (int i = 0; i < 4; ++i) {
        int vloc = w * 4 + i;
        ushort4 p = make_ushort4(f2bfbits(f0v[i]), f2bfbits(lap[i]),
                                 f2bfbits(ewا[i]), f2bfbits(ns_[i]));
        *(ushort4*)&feat[vloc * 264 + c * 4] = p;        // 8B, 2-way (free)
    }
    __syncthreads();

    // ---- phase 2: MFMA. wave w: o-tile = w&3, v-half = w>>2 ----
    int m = lane & 15, quad = lane >> 4;
    int ot = w & 3, vh = w >> 2;
    float bo = bias[ot * 16 + m];
    floatx4 acc = {bo, bo, bo, bo};
#pragma unroll
    for (int kk = 0; kk < 8; ++kk) {
        short8 a = *(const short8*)&feat[(vh * 16 + m) * 264 + kk * 32 + quad * 8];
        short8 bfr = *(const short8*)&coeffsB[((ot * 8 + kk) * 64 + lane) * 8];
        acc = __builtin_amdgcn_mfma_f32_16x16x32_bf16(a, bfr, acc, 0, 0, 0);
    }

    // ---- epilogue: C layout col=lane&15 (o), row=quad*4+reg (v) ----
#pragma unroll
    for (int r = 0; r < 4; ++r)
        outs[(vh * 16 + quad * 4 + r) * 65 + ot * 16 + m] = acc[r];
    __syncthreads();
    int vp = threadIdx.x & 31;          // 32 consecutive v -> 128 B lines
    int og = threadIdx.x >> 5;          // 0..15
    if (vb + vp < NV) {
#pragma unroll
        for (int r = 0; r < 4; ++r) {
            int o2 = og + r * 16;
            out[(size_t)o2 * NV + vb + vp] = outs[vp * 65 + o2];
        }
    }
}

// ---------------------------------------------------------------------------
extern "C" void kernel_launch(void* const* d_in, const int* in_sizes, int n_in,
                              void* d_out, int out_size, void* d_ws, size_t ws_size,
                              hipStream_t stream) {
    const float* x        = (const float*)d_in[0];
    const int*   G_cols   = (const int*)  d_in[2];
    const float* G_vals   = (const float*)d_in[3];
    const int*   L_cols   = (const int*)  d_in[5];
    const float* L_vals   = (const float*)d_in[6];
    const int*   F2V_cols = (const int*)  d_in[8];
    const float* F2V_vals = (const float*)d_in[9];
    const float* EW       = (const float*)d_in[10];
    const float* NS       = (const float*)d_in[11];
    const float* coeffs   = (const float*)d_in[12];
    const float* bias     = (const float*)d_in[13];
    float* out = (float*)d_out;

    char* ws = (char*)d_ws;
    const size_t xin_b = (size_t)NV * 64;   // elements per batch
    const size_t gf_b  = (size_t)NF * 64;
    const size_t gpk_bytes = (size_t)NF * 128;   // 10.49 MB
    const size_t vpk_bytes = (size_t)NV * 128;   // 5.24 MB
    const size_t fixed = 65536 + gpk_bytes + vpk_bytes;
    // per-batch bytes: xin bf16 2*xin_b + gfi 2*gf_b + xin8 1*xin_b
    size_t perb = 2 * xin_b + 2 * gf_b + xin_b;
    int nb = (ws_size >= fixed + 8 * perb) ? 8
           : (ws_size >= fixed + 2 * perb) ? 2 : 1;

    unsigned short* coeffsB = (unsigned short*)ws;            // 32 KB
    float* Gpk = (float*)(ws + 65536);
    float* Vpk = Gpk + (size_t)NF * 32;
    unsigned short* xin  = (unsigned short*)(ws + fixed);     // nb*5.25 MB
    unsigned short* gfi  = xin + (size_t)nb * xin_b;          // nb*10.5 MB
    unsigned char*  xin8 = (unsigned char*)(gfi + (size_t)nb * gf_b); // nb*2.6MB

    k_coeffsB<<<64, 256, 0, stream>>>(coeffs, coeffsB);
    k_packG<<<NF / 256, 256, 0, stream>>>(G_cols, G_vals, EW, NS, Gpk);
    k_packV<<<(NV + 255) / 256, 256, 0, stream>>>(L_cols, L_vals,
                                                  F2V_cols, F2V_vals, Vpk);
    for (int b0 = 0; b0 < 8; b0 += nb) {
        dim3 gt(641, nb), gg(NF / (4 * FPW), nb), gv((NV + VPB - 1) / VPB, nb);
        k_transpose<<<gt, 256, 0, stream>>>(x + (size_t)b0 * 64 * NVP, xin, xin8);
        k_facegrad<<<gg, 256, 0, stream>>>(xin8, Gpk, gfi);
        k_vertex<<<gv, 512, 0, stream>>>(xin, xin8, Vpk, gfi, coeffsB, bias,
                                         out + (size_t)b0 * 64 * NV);
    }
}